// Round 1
// baseline (17445.659 us; speedup 1.0000x reference)
//
#include <hip/hip_runtime.h>

typedef __bf16 bf16x8 __attribute__((ext_vector_type(8)));
typedef float f32x4 __attribute__((ext_vector_type(4)));

#define DEV static __device__ __forceinline__

DEV float bf2f(unsigned short u){ union { unsigned u; float f; } x; x.u = ((unsigned)u) << 16; return x.f; }
DEV unsigned short f2bf(float f){
  union { float f; unsigned u; } x; x.f = f;
  unsigned r = x.u + 0x7fffu + ((x.u >> 16) & 1u);
  return (unsigned short)(r >> 16);
}
DEV unsigned pack2(unsigned short lo, unsigned short hi){ return (unsigned)lo | ((unsigned)hi << 16); }
DEV float sigm(float x){ return 1.0f / (1.0f + expf(-x)); }

// ---------------- f32 -> bf16 convert (n4 = count/4) ----------------
__global__ void k_f2bf(const float4* __restrict__ in, uint2* __restrict__ out, long n4){
  long stride = (long)gridDim.x * blockDim.x;
  for (long i = (long)blockIdx.x * blockDim.x + threadIdx.x; i < n4; i += stride){
    float4 v = in[i];
    uint2 o; o.x = pack2(f2bf(v.x), f2bf(v.y)); o.y = pack2(f2bf(v.z), f2bf(v.w));
    out[i] = o;
  }
}

// transpose Ws_att (512x512 f32, [a][k]) -> bf16 [k][a]
__global__ void k_wst(const float* __restrict__ in, unsigned short* __restrict__ out){
  int i = blockIdx.x * 256 + threadIdx.x;   // 262144 total
  int a = i >> 9, k = i & 511;
  out[k * 512 + a] = f2bf(in[i]);
}

__global__ void k_bias3(const float* a0, const float* b0, float* o0,
                        const float* a1, const float* b1, float* o1,
                        const float* a2, const float* b2, float* o2){
  int i = blockIdx.x * 256 + threadIdx.x;   // 2048
  o0[i] = a0[i] + b0[i];
  o1[i] = a1[i] + b1[i];
  o2[i] = a2[i] + b2[i];
}

// embedding gather -> bf16 rows. row r = pos*16 + b ; token = tok[b*128 + pos]
__global__ void k_embed(const int* __restrict__ tok, const float* __restrict__ table,
                        unsigned short* __restrict__ out){
  int r = blockIdx.x;
  int b = r & 15, pos = r >> 4;
  int idx = tok[b * 128 + pos];
  float4 v = ((const float4*)(table + (size_t)idx * 512))[threadIdx.x];  // 128 threads
  uint2 o; o.x = pack2(f2bf(v.x), f2bf(v.y)); o.y = pack2(f2bf(v.z), f2bf(v.w));
  ((uint2*)(out + (size_t)r * 512))[threadIdx.x] = o;
}

// ---------------- bf16 MFMA GEMM: C[M,N] = A[M,K] * B[N,K]^T (+bias) ----------------
// BM=BN=128, BK=64, 256 threads (4 waves, each 64x64). Reg-staged LDS, XOR swizzle.
// MODE 0: C[row*ldc+col] = v.   MODE 1: row->(t=row>>4,b=row&15), out[(b*127+t)*32000+col]=v (row<mvalid)
template<int MODE>
__global__ __launch_bounds__(256)
void gemm_bt(const unsigned short* __restrict__ A, int lda,
             const unsigned short* __restrict__ B, int ldb,
             const float* __restrict__ bias,
             float* __restrict__ C, int ldc, int K, int mvalid)
{
  __shared__ __align__(16) unsigned short As[128 * 64];
  __shared__ __align__(16) unsigned short Bs[128 * 64];
  const int tid  = threadIdx.x;
  const int lane = tid & 63, wid = tid >> 6;
  const int wm = (wid >> 1) * 64, wn = (wid & 1) * 64;
  const unsigned short* Ab = A + (size_t)blockIdx.y * 128 * lda;
  const unsigned short* Bb = B + (size_t)blockIdx.x * 128 * ldb;

  f32x4 acc[4][4] = {};
  bf16x8 ga[4], gb[4];

  // preload tile 0
  #pragma unroll
  for (int r = 0; r < 4; r++){
    int c = tid + r * 256;                       // chunk: row=c>>3, piece=c&7 (8 bf16 / 16B)
    ga[r] = *(const bf16x8*)(Ab + (size_t)(c >> 3) * lda + (c & 7) * 8);
    gb[r] = *(const bf16x8*)(Bb + (size_t)(c >> 3) * ldb + (c & 7) * 8);
  }
  const int nt = K >> 6;
  for (int t = 0; t < nt; t++){
    #pragma unroll
    for (int r = 0; r < 4; r++){
      int c = tid + r * 256;
      int slot = ((c >> 3) * 8 + ((c & 7) ^ ((c >> 3) & 7))) * 8;   // XOR swizzle, 16B units
      *(bf16x8*)(As + slot) = ga[r];
      *(bf16x8*)(Bs + slot) = gb[r];
    }
    __syncthreads();
    if (t + 1 < nt){
      int k0 = (t + 1) * 64;
      #pragma unroll
      for (int r = 0; r < 4; r++){
        int c = tid + r * 256;
        ga[r] = *(const bf16x8*)(Ab + (size_t)(c >> 3) * lda + k0 + (c & 7) * 8);
        gb[r] = *(const bf16x8*)(Bb + (size_t)(c >> 3) * ldb + k0 + (c & 7) * 8);
      }
    }
    #pragma unroll
    for (int kk = 0; kk < 2; kk++){
      bf16x8 av[4], bv[4];
      #pragma unroll
      for (int i = 0; i < 4; i++){
        int ra = wm + i * 16 + (lane & 15);
        int ua = (kk * 4 + (lane >> 4)) ^ (ra & 7);
        av[i] = *(const bf16x8*)(As + (ra * 8 + ua) * 8);
        int rb = wn + i * 16 + (lane & 15);
        int ub = (kk * 4 + (lane >> 4)) ^ (rb & 7);
        bv[i] = *(const bf16x8*)(Bs + (rb * 8 + ub) * 8);
      }
      #pragma unroll
      for (int i = 0; i < 4; i++)
        #pragma unroll
        for (int j = 0; j < 4; j++)
          acc[i][j] = __builtin_amdgcn_mfma_f32_16x16x32_bf16(av[i], bv[j], acc[i][j], 0, 0, 0);
    }
    if (t + 1 < nt) __syncthreads();
  }

  const int cb = lane & 15, rb4 = (lane >> 4) * 4;
  #pragma unroll
  for (int i = 0; i < 4; i++){
    #pragma unroll
    for (int j = 0; j < 4; j++){
      #pragma unroll
      for (int r = 0; r < 4; r++){
        int row = blockIdx.y * 128 + wm + i * 16 + rb4 + r;
        int col = blockIdx.x * 128 + wn + j * 16 + cb;
        float v = acc[i][j][r];
        if (bias) v += bias[col];
        if (MODE == 0){
          C[(size_t)row * ldc + col] = v;
        } else {
          if (row < mvalid){
            int tt = row >> 4, b = row & 15;
            C[((size_t)b * 127 + tt) * 32000 + col] = v;
          }
        }
      }
    }
  }
}

// ---------------- fused encoder LSTM step (both directions) ----------------
// grid 64: dir = bx>>5, j-chunk = bx&31 (16 j per chunk). 256 thr: b=tid&15, jj=tid>>4.
__global__ __launch_bounds__(256)
void enc_step(const float* __restrict__ gin_f, const float* __restrict__ gin_b,
              const float* __restrict__ Whh_f, const float* __restrict__ Whh_b,
              float* __restrict__ h_enc,   /* [2 parity][2 dir][16][512] */
              float* __restrict__ c_enc,   /* [2 dir][16][512] */
              float* __restrict__ enc_out, /* [16][128][1024] f32 */
              unsigned short* __restrict__ enc_out_bf, /* same layout, bf16 */
              int t)
{
  __shared__ float hl[512 * 17];
  const int bx = blockIdx.x;
  const int dir = bx >> 5, chunk = bx & 31;
  const int tid = threadIdx.x;
  const int b = tid & 15, jj = tid >> 4;
  const int j = chunk * 16 + jj;
  const int p = t & 1;
  const float* gin = dir ? gin_b : gin_f;
  const float* Whh = dir ? Whh_b : Whh_f;
  const int s_in = dir ? (127 - t) : t;
  const float* hprev = h_enc + (size_t)(p * 2 + dir) * 8192;
  float* hnext       = h_enc + (size_t)(((p ^ 1) * 2) + dir) * 8192;
  float* c = c_enc + (size_t)dir * 8192;

  for (int e = tid; e < 8192; e += 256){
    int bb = e >> 9, k = e & 511;
    hl[k * 17 + bb] = hprev[bb * 512 + k];
  }
  __syncthreads();

  const float* grow = gin + (size_t)(s_in * 16 + b) * 2048;
  float a0 = grow[j], a1 = grow[512 + j], a2 = grow[1024 + j], a3 = grow[1536 + j];
  const float* w0 = Whh + (size_t)j * 512;
  const float* w1 = Whh + (size_t)(512 + j) * 512;
  const float* w2 = Whh + (size_t)(1024 + j) * 512;
  const float* w3 = Whh + (size_t)(1536 + j) * 512;

  for (int k = 0; k < 512; k += 4){
    float4 x0 = *(const float4*)(w0 + k);
    float4 x1 = *(const float4*)(w1 + k);
    float4 x2 = *(const float4*)(w2 + k);
    float4 x3 = *(const float4*)(w3 + k);
    float h0 = hl[(k + 0) * 17 + b], h1 = hl[(k + 1) * 17 + b];
    float h2 = hl[(k + 2) * 17 + b], h3 = hl[(k + 3) * 17 + b];
    a0 += x0.x * h0 + x0.y * h1 + x0.z * h2 + x0.w * h3;
    a1 += x1.x * h0 + x1.y * h1 + x1.z * h2 + x1.w * h3;
    a2 += x2.x * h0 + x2.y * h1 + x2.z * h2 + x2.w * h3;
    a3 += x3.x * h0 + x3.y * h1 + x3.z * h2 + x3.w * h3;
  }
  float ig = sigm(a0), fg = sigm(a1), gg = tanhf(a2), og = sigm(a3);
  float cv = c[b * 512 + j];
  float cn = fg * cv + ig * gg;
  float hv = og * tanhf(cn);
  c[b * 512 + j] = cn;
  hnext[b * 512 + j] = hv;
  size_t eo = ((size_t)b * 128 + s_in) * 1024 + dir * 512 + j;
  enc_out[eo] = hv;
  enc_out_bf[eo] = f2bf(hv);
}

// ---------------- h0/c0 ----------------
__global__ __launch_bounds__(512)
void k_h0c0(const float* __restrict__ h_enc, const float* __restrict__ Wbh, const float* __restrict__ bbh,
            const float* __restrict__ Wbc, const float* __restrict__ bbc,
            float* __restrict__ h_dec, float* __restrict__ c_dec)
{
  __shared__ float hc[1024];
  int b = blockIdx.x >> 1, which = blockIdx.x & 1;
  int tid = threadIdx.x;
  hc[tid]       = h_enc[b * 512 + tid];          // final forward h (parity 0, dir 0)
  hc[512 + tid] = h_enc[8192 + b * 512 + tid];   // final backward h (parity 0, dir 1)
  __syncthreads();
  const float* W = which ? Wbc : Wbh;
  float acc = (which ? bbc : bbh)[tid];
  const float* wr = W + (size_t)tid * 1024;
  for (int k = 0; k < 1024; k += 4){
    float4 w = *(const float4*)(wr + k);
    acc += w.x * hc[k] + w.y * hc[k + 1] + w.z * hc[k + 2] + w.w * hc[k + 3];
  }
  float v = tanhf(acc);
  if (which) c_dec[b * 512 + tid] = v;
  else       h_dec[b * 512 + tid] = v;
}

// ---------------- decoder attention step (one block per batch) ----------------
__global__ __launch_bounds__(512)
void attn_step(const float* __restrict__ h_dec, const unsigned short* __restrict__ WsT,
               const float* __restrict__ v_att, const float* __restrict__ enc_proj,
               const float* __restrict__ enc_out, const int* __restrict__ src_lens,
               float* __restrict__ ctx, unsigned short* __restrict__ hctx, int t)
{
  __shared__ float hl[512];
  __shared__ float hs[512];
  __shared__ float sc[128];
  const int b = blockIdx.x, tid = threadIdx.x;
  const int p = t & 1;
  hl[tid] = h_dec[(size_t)p * 8192 + b * 512 + tid];
  __syncthreads();
  // hs_att = h @ Ws_att^T  (WsT is [k][a], bf16)
  float acc = 0.f;
  #pragma unroll 8
  for (int k = 0; k < 512; k++)
    acc += hl[k] * bf2f(WsT[k * 512 + tid]);
  hs[tid] = acc;
  __syncthreads();
  // scores: 4 lanes per s
  {
    const int s = tid >> 2, part = tid & 3;
    const float* ep = enc_proj + ((size_t)b * 128 + s) * 512;
    float sa = 0.f;
    for (int a = part; a < 512; a += 4)
      sa += v_att[a] * tanhf(ep[a] + hs[a]);
    sa += __shfl_xor(sa, 1);
    sa += __shfl_xor(sa, 2);
    if (part == 0) sc[s] = sa;
  }
  __syncthreads();
  if (tid < 64){
    int slen = src_lens[b];
    float x0 = (tid < slen)      ? sc[tid]      : -1e9f;
    float x1 = (tid + 64 < slen) ? sc[tid + 64] : -1e9f;
    float m = fmaxf(x0, x1);
    #pragma unroll
    for (int o = 32; o; o >>= 1) m = fmaxf(m, __shfl_xor(m, o));
    float e0 = expf(x0 - m), e1 = expf(x1 - m);
    float ssum = e0 + e1;
    #pragma unroll
    for (int o = 32; o; o >>= 1) ssum += __shfl_xor(ssum, o);
    float inv = 1.0f / ssum;
    sc[tid] = e0 * inv; sc[tid + 64] = e1 * inv;
  }
  __syncthreads();
  const float* eo = enc_out + (size_t)b * 131072;
  float c0 = 0.f, c1 = 0.f;
  for (int s2 = 0; s2 < 128; s2++){
    float a = sc[s2];
    c0 += a * eo[s2 * 1024 + tid];
    c1 += a * eo[s2 * 1024 + 512 + tid];
  }
  ctx[b * 1024 + tid] = c0;
  ctx[b * 1024 + 512 + tid] = c1;
  size_t row = (size_t)t * 16 + b;
  hctx[row * 1536 + 512 + tid]  = f2bf(c0);
  hctx[row * 1536 + 1024 + tid] = f2bf(c1);
}

// ---------------- decoder gates + cell ----------------
// grid 128 (j-chunks of 4). 256 thr: b=tid&15, idx=tid>>4 -> g=idx>>2, jo=idx&3. n = g*512 + j0 + jo.
__global__ __launch_bounds__(256)
void dec_gates(const float* __restrict__ ctx, float* __restrict__ h_dec,
               const float* __restrict__ Wih_d, const float* __restrict__ Whh_d,
               const float* __restrict__ gin_d, float* __restrict__ c_dec,
               unsigned short* __restrict__ hctx, int t)
{
  __shared__ float xl[128 * 17];
  __shared__ float gl[4][4][16];
  const int tid = threadIdx.x;
  const int b = tid & 15, idx = tid >> 4;
  const int g = idx >> 2, jo = idx & 3;
  const int j0 = blockIdx.x * 4;
  const int n = g * 512 + j0 + jo;
  const int p = t & 1;
  const float* h = h_dec + (size_t)p * 8192;
  float* hn      = h_dec + (size_t)(p ^ 1) * 8192;

  float acc = gin_d[((size_t)t * 16 + b) * 2048 + n];

  for (int ch = 0; ch < 12; ch++){
    __syncthreads();
    #pragma unroll
    for (int e = tid; e < 2048; e += 256){
      int bb = e >> 7, kk = e & 127;
      int kg = ch * 128 + kk;
      xl[kk * 17 + bb] = (kg < 1024) ? ctx[bb * 1024 + kg] : h[bb * 512 + (kg - 1024)];
    }
    __syncthreads();
    const float* W = (ch < 8) ? (Wih_d + (size_t)n * 1536 + 512 + ch * 128)
                              : (Whh_d + (size_t)n * 512 + (ch - 8) * 128);
    for (int kk = 0; kk < 128; kk += 4){
      float4 w = *(const float4*)(W + kk);
      acc += w.x * xl[(kk + 0) * 17 + b] + w.y * xl[(kk + 1) * 17 + b]
           + w.z * xl[(kk + 2) * 17 + b] + w.w * xl[(kk + 3) * 17 + b];
    }
  }
  __syncthreads();
  gl[g][jo][b] = acc;
  __syncthreads();
  if (idx < 4){
    int j = j0 + idx;
    float ig = sigm(gl[0][idx][b]);
    float fg = sigm(gl[1][idx][b]);
    float gg = tanhf(gl[2][idx][b]);
    float og = sigm(gl[3][idx][b]);
    float cv = c_dec[b * 512 + j];
    float cn = fg * cv + ig * gg;
    float hv = og * tanhf(cn);
    c_dec[b * 512 + j] = cn;
    hn[b * 512 + j] = hv;
    hctx[((size_t)t * 16 + b) * 1536 + j] = f2bf(hv);
  }
}

extern "C" void kernel_launch(void* const* d_in, const int* in_sizes, int n_in,
                              void* d_out, int out_size, void* d_ws, size_t ws_size,
                              hipStream_t stream)
{
  const int*   src       = (const int*)d_in[0];
  const int*   src_lens  = (const int*)d_in[1];
  const int*   tgt       = (const int*)d_in[2];
  const float* enc_embed = (const float*)d_in[3];
  const float* Wih_f = (const float*)d_in[4];
  const float* Whh_f = (const float*)d_in[5];
  const float* bih_f = (const float*)d_in[6];
  const float* bhh_f = (const float*)d_in[7];
  const float* Wih_b = (const float*)d_in[8];
  const float* Whh_b = (const float*)d_in[9];
  const float* bih_b = (const float*)d_in[10];
  const float* bhh_b = (const float*)d_in[11];
  const float* Wbh = (const float*)d_in[12];
  const float* bbh = (const float*)d_in[13];
  const float* Wbc = (const float*)d_in[14];
  const float* bbc = (const float*)d_in[15];
  const float* Wh_att = (const float*)d_in[16];
  const float* Ws_att = (const float*)d_in[17];
  const float* v_att  = (const float*)d_in[18];
  const float* dec_embed = (const float*)d_in[19];
  const float* Wih_d = (const float*)d_in[20];
  const float* Whh_d = (const float*)d_in[21];
  const float* bih_d = (const float*)d_in[22];
  const float* bhh_d = (const float*)d_in[23];
  const float* Wfc = (const float*)d_in[24];
  const float* bfc = (const float*)d_in[25];
  float* out = (float*)d_out;

  char* base = (char*)d_ws;
  size_t off = 0;
  auto take = [&](size_t bytes) -> char* {
    char* p = base + off;
    off += (bytes + 255) & ~(size_t)255;
    return p;
  };
  unsigned short* wfc_bf    = (unsigned short*)take((size_t)32000 * 1536 * 2);
  unsigned short* emb_e     = (unsigned short*)take((size_t)2048 * 512 * 2);
  unsigned short* emb_d     = (unsigned short*)take((size_t)2048 * 512 * 2);
  unsigned short* wihf_bf   = (unsigned short*)take((size_t)2048 * 512 * 2);
  unsigned short* wihb_bf   = (unsigned short*)take((size_t)2048 * 512 * 2);
  unsigned short* wihd_bf   = (unsigned short*)take((size_t)2048 * 1536 * 2);
  unsigned short* whatt_bf  = (unsigned short*)take((size_t)512 * 1024 * 2);
  unsigned short* wst_bf    = (unsigned short*)take((size_t)512 * 512 * 2);
  float* gin_f    = (float*)take((size_t)2048 * 2048 * 4);
  float* gin_b    = (float*)take((size_t)2048 * 2048 * 4);
  float* gin_d    = (float*)take((size_t)2048 * 2048 * 4);
  float* enc_out  = (float*)take((size_t)16 * 128 * 1024 * 4);
  unsigned short* enc_out_bf = (unsigned short*)take((size_t)2048 * 1024 * 2);
  float* enc_proj = (float*)take((size_t)2048 * 512 * 4);
  unsigned short* hctx = (unsigned short*)take((size_t)2048 * 1536 * 2);
  float* h_enc = (float*)take((size_t)2 * 2 * 16 * 512 * 4);
  float* c_enc = (float*)take((size_t)2 * 16 * 512 * 4);
  float* h_dec = (float*)take((size_t)2 * 16 * 512 * 4);
  float* c_dec = (float*)take((size_t)16 * 512 * 4);
  float* ctxb  = (float*)take((size_t)16 * 1024 * 4);
  float* bias_f = (float*)take(2048 * 4);
  float* bias_b = (float*)take(2048 * 4);
  float* bias_d = (float*)take(2048 * 4);

  // zero: encoder/decoder state region, padded dec-embedding rows, padded hctx rows
  hipMemsetAsync(h_enc, 0, (size_t)((char*)ctxb - (char*)h_enc) + 16 * 1024 * 4, stream);
  hipMemsetAsync(emb_d, 0, (size_t)2048 * 512 * 2, stream);
  hipMemsetAsync(hctx, 0, (size_t)2048 * 1536 * 2, stream);

  // weight conversions
  k_f2bf<<<4096, 256, 0, stream>>>((const float4*)Wfc,   (uint2*)wfc_bf,   (long)32000 * 1536 / 4);
  k_f2bf<<<512,  256, 0, stream>>>((const float4*)Wih_f, (uint2*)wihf_bf,  (long)2048 * 512 / 4);
  k_f2bf<<<512,  256, 0, stream>>>((const float4*)Wih_b, (uint2*)wihb_bf,  (long)2048 * 512 / 4);
  k_f2bf<<<1024, 256, 0, stream>>>((const float4*)Wih_d, (uint2*)wihd_bf,  (long)2048 * 1536 / 4);
  k_f2bf<<<512,  256, 0, stream>>>((const float4*)Wh_att,(uint2*)whatt_bf, (long)512 * 1024 / 4);
  k_wst<<<1024, 256, 0, stream>>>(Ws_att, wst_bf);
  k_bias3<<<8, 256, 0, stream>>>(bih_f, bhh_f, bias_f, bih_b, bhh_b, bias_b, bih_d, bhh_d, bias_d);

  // embeddings (bf16), rows r = pos*16 + b
  k_embed<<<2048, 128, 0, stream>>>(src, enc_embed, emb_e);
  k_embed<<<2032, 128, 0, stream>>>(tgt, dec_embed, emb_d);

  // input-side gate GEMMs (hoisted out of the scans)
  gemm_bt<0><<<dim3(16, 16), 256, 0, stream>>>(emb_e, 512, wihf_bf, 512,  bias_f, gin_f, 2048, 512, 4096);
  gemm_bt<0><<<dim3(16, 16), 256, 0, stream>>>(emb_e, 512, wihb_bf, 512,  bias_b, gin_b, 2048, 512, 4096);
  gemm_bt<0><<<dim3(16, 16), 256, 0, stream>>>(emb_d, 512, wihd_bf, 1536, bias_d, gin_d, 2048, 512, 4096);

  // encoder: 128 fused steps (both directions per launch)
  for (int t = 0; t < 128; t++)
    enc_step<<<64, 256, 0, stream>>>(gin_f, gin_b, Whh_f, Whh_b, h_enc, c_enc, enc_out, enc_out_bf, t);

  k_h0c0<<<32, 512, 0, stream>>>(h_enc, Wbh, bbh, Wbc, bbc, h_dec, c_dec);

  // enc_proj = enc_out @ Wh_att^T
  gemm_bt<0><<<dim3(4, 16), 256, 0, stream>>>(enc_out_bf, 1024, whatt_bf, 1024, nullptr, enc_proj, 512, 1024, 4096);

  // decoder: 127 steps, 2 kernels each; logits deferred via hctx
  for (int t = 0; t < 127; t++){
    attn_step<<<16, 512, 0, stream>>>(h_dec, wst_bf, v_att, enc_proj, enc_out, src_lens, ctxb, hctx, t);
    dec_gates<<<128, 256, 0, stream>>>(ctxb, h_dec, Wih_d, Whh_d, gin_d, c_dec, hctx, t);
  }

  // one big logits GEMM: [2032,1536] x [32000,1536]^T + bfc -> out (B,T-1,V)
  gemm_bt<1><<<dim3(250, 16), 256, 0, stream>>>(hctx, 1536, wfc_bf, 1536, bfc, out, 32000, 1536, 2032);
}